// Round 2
// baseline (1116.128 us; speedup 1.0000x reference)
//
#include <hip/hip_runtime.h>
#include <cstdint>
#include <cstddef>

#define DEV __device__ __forceinline__

// ---------------- problem constants ----------------
constexpr size_t W_TOT = 131712;   // meta-param count
// region offsets inside a G / p_flat vector
constexpr size_t OFF_W1 = 0;       // [128][256]
constexpr size_t OFF_B1 = 32768;   // [256]
constexpr size_t OFF_W2 = 33024;   // [256][256]
constexpr size_t OFF_B2 = 98560;   // [256]
constexpr size_t OFF_W3 = 98816;   // [256][128]
constexpr size_t OFF_B3 = 131584;  // [128]

// ---------------- workspace layout (floats) ----------------
constexpr size_t WS_LOSS   = 0;                    // [4][64] per-wg loss partials
constexpr size_t WS_WA     = 256;                  // [8][32]
constexpr size_t WS_WU     = 512;                  // [8][32]
constexpr size_t WS_FTOT   = 768;                  // [8]
constexpr size_t WS_HP     = 1024;                 // [256][4] lr,f,beta,pad
constexpr size_t WS_H2PI   = 2048;                 // [256][128]
constexpr size_t WS_KEYS   = WS_H2PI + 32768;      // [256][128]
constexpr size_t WS_VALS   = WS_KEYS + 32768;      // [256][128]
constexpr size_t WS_D3     = WS_VALS + 32768;      // [256][128]
constexpr size_t WS_H1S    = WS_D3 + 32768;        // [256][256]
constexpr size_t WS_H2S    = WS_H1S + 65536;       // [256][256]
constexpr size_t WS_D1S    = WS_H2S + 65536;       // [256][256]
constexpr size_t WS_D2S    = WS_D1S + 65536;       // [256][256]
constexpr size_t WS_STRUCT = WS_D2S + 65536;       // [256][128]
constexpr size_t WS_TRANS  = WS_STRUCT + 32768;    // [256][16384]

// ================= generic batched-row dense layer =================
// out[r][j] = act(sum_i in[r][i]*W[i][j] + b[j]) for R rows; W streamed
// coalesced across threads, reused R times from LDS-resident inputs.
template<int R>
DEV void layerR(int IN, int OUT,
                const float* __restrict__ W, const float* __restrict__ bias,
                const float* in, int is, float* out, int os, int act)
{
  for (int j = (int)threadIdx.x; j < OUT; j += (int)blockDim.x) {
    float acc[R];
#pragma unroll
    for (int r = 0; r < R; ++r) acc[r] = 0.f;
    int i = 0;
    for (; i + 4 <= IN; i += 4) {
      const float w0 = W[(size_t)(i + 0) * OUT + j];
      const float w1 = W[(size_t)(i + 1) * OUT + j];
      const float w2 = W[(size_t)(i + 2) * OUT + j];
      const float w3 = W[(size_t)(i + 3) * OUT + j];
#pragma unroll
      for (int r = 0; r < R; ++r) {
        const float* ip = in + (size_t)r * is + i;
        acc[r] = fmaf(ip[0], w0, acc[r]);
        acc[r] = fmaf(ip[1], w1, acc[r]);
        acc[r] = fmaf(ip[2], w2, acc[r]);
        acc[r] = fmaf(ip[3], w3, acc[r]);
      }
    }
    for (; i < IN; ++i) {
      const float w0 = W[(size_t)i * OUT + j];
#pragma unroll
      for (int r = 0; r < R; ++r) acc[r] = fmaf(in[(size_t)r * is + i], w0, acc[r]);
    }
#pragma unroll
    for (int r = 0; r < R; ++r) {
      float v = acc[r] + (bias ? bias[j] : 0.f);
      if (act) v = fmaxf(v, 0.f);
      out[(size_t)r * os + j] = v;
    }
  }
  __syncthreads();
}

// ================= K1a: action MLP first two layers =================
__global__ __launch_bounds__(128) void k_pi_h2(
    const float* __restrict__ actions,
    const float* __restrict__ w1, const float* __restrict__ b1,
    const float* __restrict__ w2, const float* __restrict__ b2,
    float* __restrict__ h2out)
{
  const int row = blockIdx.x;
  const int j = threadIdx.x;
  __shared__ float a[32];
  __shared__ float h1[128];
  if (j < 32) a[j] = actions[row * 32 + j];
  __syncthreads();
  float acc = b1[j];
#pragma unroll
  for (int i = 0; i < 32; ++i) acc = fmaf(a[i], w1[i * 128 + j], acc);
  h1[j] = fmaxf(acc, 0.f);
  __syncthreads();
  float acc2 = b2[j];
#pragma unroll 8
  for (int i = 0; i < 128; ++i) acc2 = fmaf(h1[i], w2[i * 128 + j], acc2);
  h2out[row * 128 + j] = fmaxf(acc2, 0.f);
}

// ================= K1b: big matmul h2[256,128] @ W3[128,16384] =================
// grid (64 col-blocks of 256, 8 row-blocks of 32); W3 streamed to regs, h2 block in LDS.
__global__ __launch_bounds__(256) void k_pi_trans(
    const float* __restrict__ h2,
    const float* __restrict__ w3, const float* __restrict__ b3,
    float* __restrict__ trans)
{
  const int col = blockIdx.x * 256 + threadIdx.x;
  const int r0 = blockIdx.y * 32;
  __shared__ float h2s[32][128];
  for (int idx = threadIdx.x; idx < 32 * 128; idx += 256)
    h2s[idx >> 7][idx & 127] = h2[(size_t)(r0 + (idx >> 7)) * 128 + (idx & 127)];
  __syncthreads();
  float acc[32];
#pragma unroll
  for (int r = 0; r < 32; ++r) acc[r] = 0.f;
  for (int i = 0; i < 128; i += 8) {
    float w[8];
#pragma unroll
    for (int c = 0; c < 8; ++c) w[c] = w3[(size_t)(i + c) * 16384 + col];
#pragma unroll
    for (int r = 0; r < 32; ++r) {
      float s = acc[r];
#pragma unroll
      for (int c = 0; c < 8; ++c) s = fmaf(h2s[r][i + c], w[c], s);
      acc[r] = s;
    }
  }
  const float bv = b3[col];
#pragma unroll
  for (int r = 0; r < 32; ++r)
    trans[(size_t)(r0 + r) * 16384 + col] = acc[r] + bv;
}

// ================= K2: sequential RNN scan over T=32 =================
// one WG per batch b; 512 threads = 4 i-segments x 128 outputs.
__global__ __launch_bounds__(512) void k_rnn(
    const float* __restrict__ trans, const float* __restrict__ rinit,
    float* __restrict__ structural)
{
  const int b = blockIdx.x;
  const int tid = threadIdx.x;
  const int j = tid & 127, seg = tid >> 7;
  __shared__ float h[128];
  __shared__ float part[4][128];
  __shared__ float ssq;
  if (tid < 128) h[tid] = rinit[tid];
  __syncthreads();
  if (tid < 64) {
    float v = h[tid] * h[tid] + h[tid + 64] * h[tid + 64];
#pragma unroll
    for (int s = 32; s > 0; s >>= 1) v += __shfl_xor(v, s);
    if (tid == 0) ssq = v;
  }
  __syncthreads();
  if (tid < 128) h[tid] /= fmaxf(sqrtf(ssq), 1e-12f);
  __syncthreads();

  for (int t = 0; t < 32; ++t) {
    const float* Tm = trans + ((size_t)(b * 32 + t) << 14);
    float acc = 0.f;
#pragma unroll
    for (int k = 0; k < 32; ++k) {
      const int i = seg * 32 + k;
      acc = fmaf(h[i], Tm[(size_t)i * 128 + j], acc);
    }
    part[seg][j] = acc;
    __syncthreads();
    if (tid < 128) {
      float r = fmaxf(part[0][j] + part[1][j] + part[2][j] + part[3][j], 0.f);
      part[0][j] = r;
    }
    __syncthreads();
    if (tid < 64) {
      float v = part[0][tid] * part[0][tid] + part[0][tid + 64] * part[0][tid + 64];
#pragma unroll
      for (int s = 32; s > 0; s >>= 1) v += __shfl_xor(v, s);
      if (tid == 0) ssq = v;
    }
    __syncthreads();
    if (tid < 128) {
      const float nv = part[0][j] / fmaxf(sqrtf(ssq), 1e-12f);
      h[j] = nv;
      structural[(size_t)(b * 32 + t) * 128 + j] = nv;
    }
    __syncthreads();
  }
}

// ================= K3: encoder + retrieve chain + losses + keys/values/hp =================
// R=4 rows/WG, 64 WGs x 512 threads. Losses: deterministic per-WG partials.
__global__ __launch_bounds__(512) void k_stageB(
    const float* __restrict__ sensory, const float* __restrict__ enc_w,
    const float* __restrict__ dec_w, const float* __restrict__ wq,
    const float* __restrict__ wk, const float* __restrict__ wv,
    const float* __restrict__ w_hp,
    const float* __restrict__ mw1, const float* __restrict__ mb1,
    const float* __restrict__ mw2, const float* __restrict__ mb2,
    const float* __restrict__ mw3, const float* __restrict__ mb3,
    const float* __restrict__ ow1, const float* __restrict__ ob1,
    const float* __restrict__ ow2, const float* __restrict__ ob2,
    const float* __restrict__ ow3, const float* __restrict__ ob3,
    const float* __restrict__ vw1, const float* __restrict__ vb1,
    const float* __restrict__ vw2, const float* __restrict__ vb2,
    const float* __restrict__ vw3, const float* __restrict__ vb3,
    const float* __restrict__ ir,
    const float* __restrict__ structG,
    float* __restrict__ keysG, float* __restrict__ valsG, float* __restrict__ hpG,
    float* __restrict__ lossPart)
{
  const int wg = blockIdx.x;
  const int row0 = wg * 4;
  const int tid = threadIdx.x;
  __shared__ float bufA[4][512], bufB[4][512];
  __shared__ float s_struct[4][128], s_enc[4][128], s_dgs[4][128], s_corr[4][128], s_infs[4][128];
  __shared__ float sseL[4];
  __shared__ float wsum[8];

  float lgen = 0.f, lrel = 0.f, lcons = 0.f, linf = 0.f;
  const float sig_ir = 1.f / (1.f + expf(-ir[0]));

  for (int idx = tid; idx < 4 * 512; idx += 512) {
    const int r = idx >> 9, c = idx & 511;
    bufA[r][c] = sensory[(size_t)(row0 + r) * 512 + c];
  }
  for (int idx = tid; idx < 4 * 128; idx += 512) {
    const int r = idx >> 7, c = idx & 127;
    s_struct[r][c] = structG[(size_t)(row0 + r) * 128 + c];
  }
  __syncthreads();

  // enc = sensory @ enc_w (no bias, no act)
  layerR<4>(512, 128, enc_w, nullptr, &bufA[0][0], 512, &s_enc[0][0], 128, 0);

  // ---- retrieve 1: (structural, 0) ----
  layerR<4>(128, 128, wq,  nullptr, &s_struct[0][0], 128, &bufB[0][0], 512, 0);
  layerR<4>(128, 256, mw1, mb1, &bufB[0][0], 512, &bufA[0][0], 512, 1);
  layerR<4>(256, 256, mw2, mb2, &bufA[0][0], 512, &bufB[0][0], 512, 1);
  layerR<4>(256, 128, mw3, mb3, &bufB[0][0], 512, &bufA[0][0], 512, 0);
  layerR<4>(128, 256, ow1, ob1, &bufA[0][0], 512, &bufB[0][0], 512, 1);
  layerR<4>(256, 256, ow2, ob2, &bufB[0][0], 512, &bufA[0][0], 512, 1);
  layerR<4>(256, 256, ow3, ob3, &bufA[0][0], 512, &bufB[0][0], 512, 0); // d_o in bufB
  { const int r = tid >> 7, c = tid & 127; s_dgs[r][c] = bufB[r][c]; }
  __syncthreads();

  // gen loss: (dec_enc @ dec_w - sensory)^2
  {
    const int j = tid;
    float a0 = 0, a1 = 0, a2 = 0, a3 = 0;
    for (int i = 0; i < 128; ++i) {
      const float w = dec_w[(size_t)i * 512 + j];
      a0 = fmaf(bufB[0][128 + i], w, a0);
      a1 = fmaf(bufB[1][128 + i], w, a1);
      a2 = fmaf(bufB[2][128 + i], w, a2);
      a3 = fmaf(bufB[3][128 + i], w, a3);
    }
    float d;
    d = a0 - sensory[(size_t)(row0 + 0) * 512 + j]; lgen += d * d;
    d = a1 - sensory[(size_t)(row0 + 1) * 512 + j]; lgen += d * d;
    d = a2 - sensory[(size_t)(row0 + 2) * 512 + j]; lgen += d * d;
    d = a3 - sensory[(size_t)(row0 + 3) * 512 + j]; lgen += d * d;
  }
  __syncthreads();

  // ---- retrieve 2: (0, enc) ----
  layerR<4>(128, 128, wq + 128 * 128, nullptr, &s_enc[0][0], 128, &bufA[0][0], 512, 0);
  layerR<4>(128, 256, mw1, mb1, &bufA[0][0], 512, &bufB[0][0], 512, 1);
  layerR<4>(256, 256, mw2, mb2, &bufB[0][0], 512, &bufA[0][0], 512, 1);
  layerR<4>(256, 128, mw3, mb3, &bufA[0][0], 512, &bufB[0][0], 512, 0);
  layerR<4>(128, 256, ow1, ob1, &bufB[0][0], 512, &bufA[0][0], 512, 1);
  layerR<4>(256, 256, ow2, ob2, &bufA[0][0], 512, &bufB[0][0], 512, 1);
  layerR<4>(256, 256, ow3, ob3, &bufB[0][0], 512, &bufA[0][0], 512, 0); // d_o2 in bufA
  {
    const int r = tid >> 7, c = tid & 127;
    const float d = bufA[r][c] - s_struct[r][c];
    lrel += d * d;
  }
  __syncthreads();

  // ---- retrieve 3: (dec_gen_s, enc) ----
  for (int idx = tid; idx < 4 * 256; idx += 512) {
    const int r = idx >> 8, c = idx & 255;
    bufB[r][c] = (c < 128) ? s_dgs[r][c] : s_enc[r][c - 128];
  }
  __syncthreads();
  layerR<4>(256, 128, wq,  nullptr, &bufB[0][0], 512, &bufA[0][0], 512, 0);
  layerR<4>(128, 256, mw1, mb1, &bufA[0][0], 512, &bufB[0][0], 512, 1);
  layerR<4>(256, 256, mw2, mb2, &bufB[0][0], 512, &bufA[0][0], 512, 1);
  layerR<4>(256, 128, mw3, mb3, &bufA[0][0], 512, &bufB[0][0], 512, 0);
  layerR<4>(128, 256, ow1, ob1, &bufB[0][0], 512, &bufA[0][0], 512, 1);
  layerR<4>(256, 256, ow2, ob2, &bufA[0][0], 512, &bufB[0][0], 512, 1);
  layerR<4>(256, 256, ow3, ob3, &bufB[0][0], 512, &bufA[0][0], 512, 0); // d_o3 in bufA
  {
    const int r = tid >> 7, c = tid & 127;
    s_corr[r][c] = bufA[r][c];
    const float d = bufA[r][128 + c] - s_enc[r][c];
    bufB[r][c] = d * d;                                 // scratch for sse
  }
  __syncthreads();
  if (tid < 4) {
    float s = 0.f;
    for (int c = 0; c < 128; ++c) s += bufB[tid][c];
    sseL[tid] = s;
  }
  __syncthreads();

  // pred_var MLP: vin = [corr_s, dec_gen_s, sse] (257)
  for (int rr = 0; rr < 4; ++rr) {
    if (tid < 257)
      bufB[rr][tid] = (tid < 128) ? s_corr[rr][tid]
                     : (tid < 256 ? s_dgs[rr][tid - 128] : sseL[rr]);
  }
  __syncthreads();
  layerR<4>(257, 256, vw1, vb1, &bufB[0][0], 512, &bufA[0][0], 512, 1);
  layerR<4>(256, 256, vw2, vb2, &bufA[0][0], 512, &bufB[0][0], 512, 1);
  layerR<4>(256, 128, vw3, vb3, &bufB[0][0], 512, &bufA[0][0], 512, 0); // pv in bufA
  {
    const int r = tid >> 7, c = tid & 127;
    const float diff = (s_corr[r][c] - s_dgs[r][c]) * sig_ir * bufA[r][c];
    s_infs[r][c] = s_dgs[r][c] + diff;
    lcons += diff * diff;
  }
  __syncthreads();

  // ---- retrieve 4: (inf_s, 0) ----
  layerR<4>(128, 128, wq,  nullptr, &s_infs[0][0], 128, &bufB[0][0], 512, 0);
  layerR<4>(128, 256, mw1, mb1, &bufB[0][0], 512, &bufA[0][0], 512, 1);
  layerR<4>(256, 256, mw2, mb2, &bufA[0][0], 512, &bufB[0][0], 512, 1);
  layerR<4>(256, 128, mw3, mb3, &bufB[0][0], 512, &bufA[0][0], 512, 0);
  layerR<4>(128, 256, ow1, ob1, &bufA[0][0], 512, &bufB[0][0], 512, 1);
  layerR<4>(256, 256, ow2, ob2, &bufB[0][0], 512, &bufA[0][0], 512, 1);
  layerR<4>(256, 256, ow3, ob3, &bufA[0][0], 512, &bufB[0][0], 512, 0); // d_o4 in bufB
  {
    const int j = tid;
    float a0 = 0, a1 = 0, a2 = 0, a3 = 0;
    for (int i = 0; i < 128; ++i) {
      const float w = dec_w[(size_t)i * 512 + j];
      a0 = fmaf(bufB[0][128 + i], w, a0);
      a1 = fmaf(bufB[1][128 + i], w, a1);
      a2 = fmaf(bufB[2][128 + i], w, a2);
      a3 = fmaf(bufB[3][128 + i], w, a3);
    }
    float d;
    d = a0 - sensory[(size_t)(row0 + 0) * 512 + j]; linf += d * d;
    d = a1 - sensory[(size_t)(row0 + 1) * 512 + j]; linf += d * d;
    d = a2 - sensory[(size_t)(row0 + 2) * 512 + j]; linf += d * d;
    d = a3 - sensory[(size_t)(row0 + 3) * 512 + j]; linf += d * d;
  }
  __syncthreads();

  // joint = [final_s, enc]; keys/values/hp straight to workspace
  for (int idx = tid; idx < 4 * 256; idx += 512) {
    const int r = idx >> 8, c = idx & 255;
    bufA[r][c] = (c < 128) ? bufB[r][c] : s_enc[r][c - 128];
  }
  __syncthreads();
  layerR<4>(256, 128, wk,   nullptr, &bufA[0][0], 512, keysG + (size_t)row0 * 128, 128, 0);
  layerR<4>(256, 128, wv,   nullptr, &bufA[0][0], 512, valsG + (size_t)row0 * 128, 128, 0);
  layerR<4>(256, 3,   w_hp, nullptr, &bufA[0][0], 512, hpG + (size_t)row0 * 4, 4, 0);

  // deterministic per-WG loss reduce
  float l[4] = { lgen, lrel, lcons, linf };
#pragma unroll
  for (int li = 0; li < 4; ++li) {
    float v = l[li];
#pragma unroll
    for (int s = 32; s > 0; s >>= 1) v += __shfl_xor(v, s);
    if ((tid & 63) == 0) wsum[tid >> 6] = v;
    __syncthreads();
    if (tid == 0) {
      float s = 0.f;
      for (int w = 0; w < 8; ++w) s += wsum[w];
      lossPart[li * 64 + wg] = s;
    }
    __syncthreads();
  }
}

// ================= K4: per-row meta-MLP forward + backward deltas =================
__global__ __launch_bounds__(256) void k_meta(
    const float* __restrict__ keysG, const float* __restrict__ valsG,
    const float* __restrict__ mw1, const float* __restrict__ mb1,
    const float* __restrict__ mw2, const float* __restrict__ mb2,
    const float* __restrict__ mw3, const float* __restrict__ mb3,
    float* __restrict__ h1G, float* __restrict__ h2G,
    float* __restrict__ d1G, float* __restrict__ d2G, float* __restrict__ d3G)
{
  const int row0 = blockIdx.x * 4;
  const int tid = threadIdx.x;
  __shared__ float kk[4][128], vv[4][128], h1s[4][256], h2s[4][256], d3s[4][128], d2s[4][256];
  for (int idx = tid; idx < 4 * 128; idx += 256) {
    const int r = idx >> 7, c = idx & 127;
    kk[r][c] = keysG[(size_t)(row0 + r) * 128 + c];
    vv[r][c] = valsG[(size_t)(row0 + r) * 128 + c];
  }
  __syncthreads();
  layerR<4>(128, 256, mw1, mb1, &kk[0][0], 128, &h1s[0][0], 256, 1);
  layerR<4>(256, 256, mw2, mb2, &h1s[0][0], 256, &h2s[0][0], 256, 1);
  layerR<4>(256, 128, mw3, mb3, &h2s[0][0], 256, &d3s[0][0], 128, 0); // o into d3s
  for (int idx = tid; idx < 4 * 128; idx += 256) {
    const int r = idx >> 7, c = idx & 127;
    const float d = (d3s[r][c] - vv[r][c]) * (2.f / 128.f);
    d3s[r][c] = d;
    d3G[(size_t)(row0 + r) * 128 + c] = d;
  }
  for (int idx = tid; idx < 4 * 256; idx += 256) {
    const int r = idx >> 8, c = idx & 255;
    h1G[(size_t)(row0 + r) * 256 + c] = h1s[r][c];
    h2G[(size_t)(row0 + r) * 256 + c] = h2s[r][c];
  }
  __syncthreads();
  // d2[i] = relu'(h2) * sum_j W3[i][j] d3[j]
  {
    const int i = tid;
    float acc[4] = { 0, 0, 0, 0 };
    for (int jc = 0; jc < 128; jc += 4) {
      const float4 w = *reinterpret_cast<const float4*>(&mw3[(size_t)i * 128 + jc]);
#pragma unroll
      for (int r = 0; r < 4; ++r) {
        acc[r] = fmaf(w.x, d3s[r][jc + 0], acc[r]);
        acc[r] = fmaf(w.y, d3s[r][jc + 1], acc[r]);
        acc[r] = fmaf(w.z, d3s[r][jc + 2], acc[r]);
        acc[r] = fmaf(w.w, d3s[r][jc + 3], acc[r]);
      }
    }
#pragma unroll
    for (int r = 0; r < 4; ++r) {
      const float v = (h2s[r][i] > 0.f) ? acc[r] : 0.f;
      d2s[r][i] = v;
      d2G[(size_t)(row0 + r) * 256 + i] = v;
    }
  }
  __syncthreads();
  // d1[i] = relu'(h1) * sum_j W2[i][j] d2[j]
  {
    const int i = tid;
    float acc[4] = { 0, 0, 0, 0 };
    for (int jc = 0; jc < 256; jc += 4) {
      const float4 w = *reinterpret_cast<const float4*>(&mw2[(size_t)i * 256 + jc]);
#pragma unroll
      for (int r = 0; r < 4; ++r) {
        acc[r] = fmaf(w.x, d2s[r][jc + 0], acc[r]);
        acc[r] = fmaf(w.y, d2s[r][jc + 1], acc[r]);
        acc[r] = fmaf(w.z, d2s[r][jc + 2], acc[r]);
        acc[r] = fmaf(w.w, d2s[r][jc + 3], acc[r]);
      }
    }
#pragma unroll
    for (int r = 0; r < 4; ++r)
      d1G[(size_t)(row0 + r) * 256 + i] = (h1s[r][i] > 0.f) ? acc[r] : 0.f;
  }
}

// ================= K5: closed-form scan coefficients =================
// update_T = sum_t lr_t*cB_t*G_t ; acc_T = Ftot*p - sum_t lr_t*B_t*G_t
__global__ __launch_bounds__(256) void k_coef(
    const float* __restrict__ hp, float* __restrict__ wA,
    float* __restrict__ wU, float* __restrict__ Ftot)
{
  __shared__ float sb[8][32], sf[8][32], lr[8][32];
  const int tid = threadIdx.x;
  for (int idx = tid; idx < 256; idx += 256) {
    const int b = idx >> 5, t = idx & 31;
    lr[b][t] = hp[idx * 4 + 0];
    sf[b][t] = 1.f / (1.f + expf(-hp[idx * 4 + 1]));
    sb[b][t] = 1.f / (1.f + expf(-hp[idx * 4 + 2]));
  }
  __syncthreads();
  if (tid < 8) {
    const int b = tid;
    float cB = 1.f, cF = 1.f, Bv = 1.f;
    wU[b * 32 + 31] = lr[b][31];
    wA[b * 32 + 31] = lr[b][31];
    for (int t = 30; t >= 0; --t) {
      cB = sb[b][t + 1] * cB;
      cF = sf[b][t + 1] * cF;
      Bv = cF + sb[b][t + 1] * Bv;
      wU[b * 32 + t] = lr[b][t] * cB;
      wA[b * 32 + t] = lr[b][t] * Bv;
    }
    float ft = 1.f;
    for (int t = 0; t < 32; ++t) ft *= sf[b][t];
    Ftot[b] = ft;
  }
}

// ================= K6: weighted outer-product accumulation (weight blocks) =================
// out_acc[i][j] = Ftot*P[i][j] - sum_t wA_t * L_t[i] * D_t[j]
// out_upd[i][j] =               sum_t wU_t * L_t[i] * D_t[j]
__global__ __launch_bounds__(256) void k_outer(
    const float* __restrict__ L, int Lld,
    const float* __restrict__ D, int Dld,
    const float* __restrict__ P,
    const float* __restrict__ wA, const float* __restrict__ wU,
    const float* __restrict__ Ftot,
    float* __restrict__ out, size_t regionOff, int J)
{
  const int b = blockIdx.x;
  const int i0 = blockIdx.y * 32;
  const int tid = threadIdx.x;
  __shared__ float wAk[32][33], wUk[32][33];
  for (int idx = tid; idx < 1024; idx += 256) {
    const int t = idx >> 5, ii = idx & 31;
    const float kv = L[(size_t)(b * 32 + t) * Lld + i0 + ii];
    wAk[t][ii] = wA[b * 32 + t] * kv;
    wUk[t][ii] = wU[b * 32 + t] * kv;
  }
  __syncthreads();
  const int j = (J == 256) ? tid : (tid & 127);
  const int g = (J == 256) ? 0 : (tid >> 7);
  const int span = (J == 256) ? 32 : 16;
  const int iBeg = g * span;
  float dv[32];
#pragma unroll
  for (int t = 0; t < 32; ++t) dv[t] = D[(size_t)(b * 32 + t) * Dld + j];
  const float ft = Ftot[b];
  float* ob = out + 1 + (size_t)b * (2 * W_TOT);
  for (int ii = iBeg; ii < iBeg + span; ++ii) {
    float aA = 0.f, aU = 0.f;
#pragma unroll
    for (int t = 0; t < 32; ++t) {
      aA = fmaf(wAk[t][ii], dv[t], aA);
      aU = fmaf(wUk[t][ii], dv[t], aU);
    }
    const int i = i0 + ii;
    const size_t w = regionOff + (size_t)i * J + j;
    ob[w] = ft * P[(size_t)i * J + j] - aA;
    ob[W_TOT + w] = aU;
  }
}

// ================= K6d: bias blocks =================
__global__ __launch_bounds__(256) void k_bias(
    const float* __restrict__ d1s, const float* __restrict__ d2s,
    const float* __restrict__ d3s,
    const float* __restrict__ mb1, const float* __restrict__ mb2,
    const float* __restrict__ mb3,
    const float* __restrict__ wA, const float* __restrict__ wU,
    const float* __restrict__ Ftot, float* __restrict__ out)
{
  const int b = blockIdx.x;
  const int tid = threadIdx.x;
  const float ft = Ftot[b];
  float* ob = out + 1 + (size_t)b * (2 * W_TOT);
  for (int idx = tid; idx < 640; idx += 256) {
    const float* D; int ld, j; size_t off; float pv;
    if (idx < 256)      { D = d1s; ld = 256; j = idx;       off = OFF_B1; pv = mb1[j]; }
    else if (idx < 512) { D = d2s; ld = 256; j = idx - 256; off = OFF_B2; pv = mb2[j]; }
    else                { D = d3s; ld = 128; j = idx - 512; off = OFF_B3; pv = mb3[j]; }
    float aA = 0.f, aU = 0.f;
#pragma unroll
    for (int t = 0; t < 32; ++t) {
      const float dv = D[(size_t)(b * 32 + t) * ld + j];
      aA = fmaf(wA[b * 32 + t], dv, aA);
      aU = fmaf(wU[b * 32 + t], dv, aU);
    }
    ob[off + j] = ft * pv - aA;
    ob[W_TOT + off + j] = aU;
  }
}

// ================= K7: finalize total loss =================
__global__ __launch_bounds__(64) void k_final(
    const float* __restrict__ lossPart, float* __restrict__ out)
{
  const int tid = threadIdx.x;
  __shared__ float s[4];
  if (tid < 4) {
    float acc = 0.f;
    for (int w = 0; w < 64; ++w) acc += lossPart[tid * 64 + w];
    s[tid] = acc;
  }
  __syncthreads();
  if (tid == 0) {
    const float i1 = 1.f / (256.f * 512.f);  // B*T*DSENS
    const float i2 = 1.f / (256.f * 128.f);  // B*T*DS
    out[0] = s[0] * i1 + 2.f * s[1] * i2 + s[2] * i2 + s[3] * i1;
  }
}

// ================= launch =================
extern "C" void kernel_launch(void* const* d_in, const int* in_sizes, int n_in,
                              void* d_out, int out_size, void* d_ws, size_t ws_size,
                              hipStream_t stream)
{
  const float* sensory = (const float*)d_in[0];
  const float* actions = (const float*)d_in[1];
  const float* enc_w = (const float*)d_in[2];
  const float* dec_w = (const float*)d_in[3];
  const float* pi_w1 = (const float*)d_in[4];
  const float* pi_b1 = (const float*)d_in[5];
  const float* pi_w2 = (const float*)d_in[6];
  const float* pi_b2 = (const float*)d_in[7];
  const float* pi_w3 = (const float*)d_in[8];
  const float* pi_b3 = (const float*)d_in[9];
  const float* rinit = (const float*)d_in[10];
  const float* wq = (const float*)d_in[11];
  const float* wk = (const float*)d_in[12];
  const float* wv = (const float*)d_in[13];
  const float* w_hp = (const float*)d_in[14];
  const float* mw1 = (const float*)d_in[15]; const float* mb1 = (const float*)d_in[16];
  const float* mw2 = (const float*)d_in[17]; const float* mb2 = (const float*)d_in[18];
  const float* mw3 = (const float*)d_in[19]; const float* mb3 = (const float*)d_in[20];
  const float* ow1 = (const float*)d_in[21]; const float* ob1 = (const float*)d_in[22];
  const float* ow2 = (const float*)d_in[23]; const float* ob2 = (const float*)d_in[24];
  const float* ow3 = (const float*)d_in[25]; const float* ob3 = (const float*)d_in[26];
  const float* vw1 = (const float*)d_in[27]; const float* vb1 = (const float*)d_in[28];
  const float* vw2 = (const float*)d_in[29]; const float* vb2 = (const float*)d_in[30];
  const float* vw3 = (const float*)d_in[31]; const float* vb3 = (const float*)d_in[32];
  const float* ir  = (const float*)d_in[33];

  float* ws  = (float*)d_ws;
  float* out = (float*)d_out;

  float* lossPart = ws + WS_LOSS;
  float* wA = ws + WS_WA;  float* wU = ws + WS_WU;  float* Ft = ws + WS_FTOT;
  float* hp = ws + WS_HP;  float* h2pi = ws + WS_H2PI;
  float* keys = ws + WS_KEYS;  float* vals = ws + WS_VALS;
  float* d3s = ws + WS_D3;  float* h1s = ws + WS_H1S;  float* h2s = ws + WS_H2S;
  float* d1s = ws + WS_D1S; float* d2s = ws + WS_D2S;
  float* structural = ws + WS_STRUCT;
  float* trans = ws + WS_TRANS;

  hipLaunchKernelGGL(k_pi_h2, dim3(256), dim3(128), 0, stream,
                     actions, pi_w1, pi_b1, pi_w2, pi_b2, h2pi);
  hipLaunchKernelGGL(k_pi_trans, dim3(64, 8), dim3(256), 0, stream,
                     h2pi, pi_w3, pi_b3, trans);
  hipLaunchKernelGGL(k_rnn, dim3(8), dim3(512), 0, stream,
                     trans, rinit, structural);
  hipLaunchKernelGGL(k_stageB, dim3(64), dim3(512), 0, stream,
                     sensory, enc_w, dec_w, wq, wk, wv, w_hp,
                     mw1, mb1, mw2, mb2, mw3, mb3,
                     ow1, ob1, ow2, ob2, ow3, ob3,
                     vw1, vb1, vw2, vb2, vw3, vb3,
                     ir, structural, keys, vals, hp, lossPart);
  hipLaunchKernelGGL(k_meta, dim3(64), dim3(256), 0, stream,
                     keys, vals, mw1, mb1, mw2, mb2, mw3, mb3,
                     h1s, h2s, d1s, d2s, d3s);
  hipLaunchKernelGGL(k_coef, dim3(1), dim3(256), 0, stream, hp, wA, wU, Ft);
  hipLaunchKernelGGL(k_outer, dim3(8, 4), dim3(256), 0, stream,
                     keys, 128, d1s, 256, mw1, wA, wU, Ft, out, OFF_W1, 256);
  hipLaunchKernelGGL(k_outer, dim3(8, 8), dim3(256), 0, stream,
                     h1s, 256, d2s, 256, mw2, wA, wU, Ft, out, OFF_W2, 256);
  hipLaunchKernelGGL(k_outer, dim3(8, 8), dim3(256), 0, stream,
                     h2s, 256, d3s, 128, mw3, wA, wU, Ft, out, OFF_W3, 128);
  hipLaunchKernelGGL(k_bias, dim3(8), dim3(256), 0, stream,
                     d1s, d2s, d3s, mb1, mb2, mb3, wA, wU, Ft, out);
  hipLaunchKernelGGL(k_final, dim3(1), dim3(64), 0, stream, lossPart, out);
}